// Round 4
// baseline (208.226 us; speedup 1.0000x reference)
//
#include <hip/hip_runtime.h>

// inputs: (B=8, C=2, D=96, H=64, W=64) f32
// weight/bias: (F=8, C=2, d=3, h=60, w=64) f32
// out: (B=8, F=8, Dout=94, h=60, w=64) f32
#define B_ 8
#define C_ 2
#define D_ 96
#define H_ 64
#define W_ 64
#define F_ 8
#define KD 3
#define h_ 60
#define Dout_ 94
#define PLANE (h_ * W_)          // 3840 floats
#define NCH (PLANE / 4)          // 960 float4 chunks per plane
#define NS2 (B_ * C_ * D_)       // 1536 s2 planes
#define S2_FLOATS ((size_t)NS2 * PLANE)
#define NDT (Dout_ / 2)          // 47 dout-pairs (94 = 47*2, no tail)
#define FT 4                     // f per block
#define NFG (F_ / FT)            // 2 f-groups

__device__ __forceinline__ float4 f4fma(float4 a, float4 b, float4 c) {
    c.x += a.x * b.x; c.y += a.y * b.y; c.z += a.z * b.z; c.w += a.w * b.w;
    return c;
}

// Horizontal 3-tap sum via lane shuffles; c4 = float4-column 0..15 within a
// 16-lane row group. Boundary cols contribute zero. Must be called by ALL
// lanes (no divergence) — pass V=0 for inactive rows.
__device__ __forceinline__ float4 hsum3(float4 V, int c4) {
    const int lane = threadIdx.x & 63;
    float lw = __shfl(V.w, (lane + 63) & 63, 64);
    float rx = __shfl(V.x, (lane + 1) & 63, 64);
    if (c4 == 0) lw = 0.f;
    if (c4 == 15) rx = 0.f;
    float4 o;
    o.x = lw + V.x + V.y;
    o.y = V.x + V.y + V.z;
    o.z = V.y + V.z + V.w;
    o.w = V.z + V.w + rx;
    return o;
}

// ---------------------------------------------------------------------------
// Prep kernel (unchanged from R3):
// Blocks 0..NS2-1:       S2[b,c,p] = vertical 5-sum of input plane.
// Blocks NS2..NS2+F_-1:  BoxBS[f]  = Box3x3( sum_{c,z} bias[f,c,z] ).
// ---------------------------------------------------------------------------
__global__ __launch_bounds__(256) void k_prep(const float* __restrict__ in,
                                              const float* __restrict__ bs,
                                              float* __restrict__ s2,
                                              float* __restrict__ bb) {
    const int bx = blockIdx.x;
    const int tid = threadIdx.x;
    __shared__ float4 lds[H_ * 16];  // 16 KB

    if (bx < NS2) {
        const float4* ip4 = (const float4*)(in + (size_t)bx * (H_ * W_));
        float4* op4 = (float4*)(s2 + (size_t)bx * PLANE);
#pragma unroll
        for (int k = 0; k < 4; ++k) lds[tid + 256 * k] = ip4[tid + 256 * k];
        __syncthreads();
#pragma unroll
        for (int k = 0; k < 4; ++k) {
            const int e = tid + 256 * k;
            if (e < NCH) {
                const int row = e >> 4, col = e & 15;
                float4 s = lds[row * 16 + col];
#pragma unroll
                for (int j = 1; j < 5; ++j) {
                    const float4 v = lds[(row + j) * 16 + col];
                    s.x += v.x; s.y += v.y; s.z += v.z; s.w += v.w;
                }
                op4[e] = s;
            }
        }
    } else {
        const int f = bx - NS2;
        float4* R = lds;  // rows 0..61, rows 0 and 61 zeroed
        if (tid < 32) {
            const int r = (tid >> 4) ? 61 : 0;
            R[r * 16 + (tid & 15)] = make_float4(0, 0, 0, 0);
        }
        const float4* bp = (const float4*)(bs + (size_t)f * (C_ * KD * PLANE));
#pragma unroll
        for (int k = 0; k < 4; ++k) {
            const int e = tid + 256 * k;
            if (e < NCH) {
                float4 s = make_float4(0, 0, 0, 0);
#pragma unroll
                for (int s6 = 0; s6 < 6; ++s6) {
                    const float4 v = bp[s6 * NCH + e];
                    s.x += v.x; s.y += v.y; s.z += v.z; s.w += v.w;
                }
                R[((e >> 4) + 1) * 16 + (e & 15)] = s;
            }
        }
        __syncthreads();
        float4* ob = (float4*)(bb + (size_t)f * PLANE);
#pragma unroll
        for (int k = 0; k < 4; ++k) {
            const int e = tid + 256 * k;
            if (e < NCH) {
                const int row = e >> 4, c4 = e & 15;
                const float4 a = R[row * 16 + c4];
                const float4 m = R[(row + 1) * 16 + c4];
                const float4 d = R[(row + 2) * 16 + c4];
                float4 V;
                V.x = a.x + m.x + d.x; V.y = a.y + m.y + d.y;
                V.z = a.z + m.z + d.z; V.w = a.w + m.w + d.w;
                ob[e] = hsum3(V, c4);
            }
        }
    }
}

// ---------------------------------------------------------------------------
// Main kernel. Block = (b, dout-pair, y-half, f-quad).
// Covers rows [y0-1, y0+30] (32 rows = 512 float4 chunks = 2/thread) incl.
// box halo. S2 windows (2c x 4 planes) pinned in registers, reused across
// 4 f x 2 douts. Weights streamed from (XCD-resident) L2 per f. Vertical
// box via ping-pong LDS (1 barrier/plane), horizontal via shuffles.
// ---------------------------------------------------------------------------
__global__ __launch_bounds__(256) void k_main(const float* __restrict__ s2,
                                              const float* __restrict__ wt,
                                              const float* __restrict__ bb,
                                              float* __restrict__ out) {
    const int bx = blockIdx.x;
    const int fg = bx & 1;                 // f-group
    const int yh = (bx >> 1) & 1;          // y-half
    const int dt = (bx >> 2) % NDT;        // dout-pair
    const int b  = bx / (4 * NDT);
    const int dout0 = dt * 2;
    const int f0 = fg * FT;
    const int tid = threadIdx.x;

    __shared__ float4 Rb[2][512];          // ping-pong, 16 KB

    int e[2], c4[2], gy[2], gyc[2];
    bool valid[2], orow[2];
#pragma unroll
    for (int k = 0; k < 2; ++k) {
        e[k] = tid + 256 * k;
        const int r = e[k] >> 4;           // local row 0..31
        c4[k] = e[k] & 15;
        gy[k] = yh * 30 - 1 + r;           // global row, -1..60
        int g = gy[k]; g = (g < 0) ? 0 : g; g = (g > 59) ? 59 : g;
        gyc[k] = g;
        valid[k] = (gy[k] >= 0) && (gy[k] <= 59);
        orow[k] = (r >= 1) && (r <= 30);   // rows we emit output for
    }

    // S2 windows into registers: [c][zz in 0..3][chunk]. 64 VGPRs.
    float4 s2r[2][4][2];
    const float4* s2f = (const float4*)s2;
#pragma unroll
    for (int c = 0; c < 2; ++c)
#pragma unroll
        for (int zz = 0; zz < 4; ++zz) {
            const size_t base = (size_t)((b * C_ + c) * D_ + dout0 + zz) * NCH;
#pragma unroll
            for (int k = 0; k < 2; ++k)
                s2r[c][zz][k] = s2f[base + gyc[k] * 16 + c4[k]];
        }

    const float4* wtf = (const float4*)wt;
    const float4* bbf = (const float4*)bb;
    const float4 z4 = make_float4(0, 0, 0, 0);

    for (int fi = 0; fi < FT; ++fi) {
        const int f = f0 + fi;

        float4 acc[2][2];
#pragma unroll
        for (int t = 0; t < 2; ++t)
#pragma unroll
            for (int k = 0; k < 2; ++k) acc[t][k] = z4;

#pragma unroll
        for (int c = 0; c < 2; ++c)
#pragma unroll
            for (int z = 0; z < KD; ++z) {
                const size_t wbase = (size_t)((f * C_ + c) * KD + z) * NCH;
                float4 w[2];
#pragma unroll
                for (int k = 0; k < 2; ++k)
                    w[k] = wtf[wbase + gyc[k] * 16 + c4[k]];
#pragma unroll
                for (int k = 0; k < 2; ++k) {
                    acc[0][k] = f4fma(w[k], s2r[c][z][k], acc[0][k]);
                    acc[1][k] = f4fma(w[k], s2r[c][z + 1][k], acc[1][k]);
                }
            }

        // Box(bias) for this f, output rows only.
        float4 bbv[2];
#pragma unroll
        for (int k = 0; k < 2; ++k)
            bbv[k] = orow[k] ? bbf[(size_t)f * NCH + gy[k] * 16 + c4[k]] : z4;

#pragma unroll
        for (int t = 0; t < 2; ++t) {
            float4* R = Rb[(fi * 2 + t) & 1];
#pragma unroll
            for (int k = 0; k < 2; ++k)
                R[e[k]] = valid[k] ? acc[t][k] : z4;  // halo rows -> 0
            __syncthreads();

            const int dout = dout0 + t;
            float4* of = (float4*)(out + (size_t)((b * F_ + f) * Dout_ + dout) * PLANE);
#pragma unroll
            for (int k = 0; k < 2; ++k) {
                float4 V = z4;
                if (orow[k]) {
                    const float4 a = R[e[k] - 16];
                    const float4 m = R[e[k]];
                    const float4 d = R[e[k] + 16];
                    V.x = a.x + m.x + d.x; V.y = a.y + m.y + d.y;
                    V.z = a.z + m.z + d.z; V.w = a.w + m.w + d.w;
                }
                float4 o = hsum3(V, c4[k]);  // all lanes: no shuffle divergence
                if (orow[k]) {
                    o.x = 0.25f * (o.x + bbv[k].x);
                    o.y = 0.25f * (o.y + bbv[k].y);
                    o.z = 0.25f * (o.z + bbv[k].z);
                    o.w = 0.25f * (o.w + bbv[k].w);
                    o.x = (o.x > 0.f) ? o.x : 0.2f * o.x;
                    o.y = (o.y > 0.f) ? o.y : 0.2f * o.y;
                    o.z = (o.z > 0.f) ? o.z : 0.2f * o.z;
                    o.w = (o.w > 0.f) ? o.w : 0.2f * o.w;
                    of[gy[k] * 16 + c4[k]] = o;
                }
            }
        }
    }
}

extern "C" void kernel_launch(void* const* d_in, const int* in_sizes, int n_in,
                              void* d_out, int out_size, void* d_ws, size_t ws_size,
                              hipStream_t stream) {
    const float* in = (const float*)d_in[0];
    const float* wt = (const float*)d_in[1];
    const float* bs = (const float*)d_in[2];
    float* out = (float*)d_out;

    float* s2 = (float*)d_ws;
    float* bb = s2 + S2_FLOATS;

    k_prep<<<dim3(NS2 + F_), dim3(256), 0, stream>>>(in, bs, s2, bb);
    // grid: b(8) x dout-pair(47) x y-half(2) x f-group(2) = 1504 blocks
    k_main<<<dim3(B_ * NDT * 2 * NFG), dim3(256), 0, stream>>>(s2, wt, bb, out);
}